// Round 5
// baseline (162.247 us; speedup 1.0000x reference)
//
#include <hip/hip_runtime.h>

// DigitCaps on MI355X, fp32 I/O, R5.
// R2: fp32 atomicAdd = CAS loop -> native int atomics only.
// R3: global seg needs int64 (winner bias -> seg ~3e5, int32@2^17 wrapped).
// R4: VGPR=220 -> 2 waves/SIMD, latency-bound (VALU 20%, HBM 2.4%); 128-blk
//     finalize with 128KB-strided gathers ate ~60us.
// R5: per-vote u[8] loop + 2 batch rows/thread (halves W LDS reads),
//     __launch_bounds__(256,4) -> <=128 VGPR -> 16 waves/CU; grid 1152;
//     s partials flushed as global i64 fixed-point atomics -> 1-block finalize.
//
// Sizes: B=128, J=4608, INPUT_D=8, D=8, M=4 -> N=18432 votes, C=10.
// Output = concat(output[128,10], digit_caps_new[10,8]).
// Math: output[b,c] = <(1/N) sum_n u[b,n], dc_new[c]> -> only s[b,:] needed.
//
// ws layout: i64[0,80) seg (scale 2^15) ; i64[128,1152) s (scale 2^20) ;
//            int at byte 9216: counts[10]. Memset first 10240 bytes.

#define J_POS 4608
#define WSTRIDE 264         // 256+8 pad
#define SEGSTRIDE 97        // 97%32=1 -> replica r shifts banks by r
#define NREP 8
#define NVOTES 18432.0f
#define DENOM  2359296.0f   // B*N
#define SEG_SCALE 32768.0f          // 2^15 (per-replica max ~8e7 < 2^31)
#define INV_SEG_SCALE 3.0517578125e-5f
#define S_SCALE 1048576.0f          // 2^20
#define INV_S_SCALE 9.5367431640625e-7f
#define WS_S_OFF 128        // in i64 units
#define WS_CNT_OFF 2304     // in int units (= byte 9216)

__global__ __launch_bounds__(256, 4) void votes_kernel(
    const float* __restrict__ x,   // [B, J, 8]
    const float* __restrict__ w,   // [J, 8, 32]
    const float* __restrict__ dc,  // [10, 8]
    unsigned long long* __restrict__ ws64,
    int* __restrict__ wsi)
{
    __shared__ float w_lds[8 * WSTRIDE];
    __shared__ __align__(16) float dc_lds[80];
    __shared__ int seg_lds[NREP * SEGSTRIDE];
    __shared__ float s_lds[64 * 8];

    const int t  = threadIdx.x;
    const int jg = blockIdx.x >> 1;     // j-group: consecutive pair shares W (L2)
    const int h  = blockIdx.x & 1;      // batch half
    const int j0 = jg * 8;

    // ---- stage W tile: 8 j * 256 floats; thread t loads 8 floats
    {
        const int idx = t * 8;
        const int jj = idx >> 8, rem = idx & 255;
        const float4 r0 = *(const float4*)(w + (size_t)j0 * 256 + idx);
        const float4 r1 = *(const float4*)(w + (size_t)j0 * 256 + idx + 4);
        float* dst = &w_lds[jj * WSTRIDE + rem];
        dst[0] = r0.x; dst[1] = r0.y; dst[2] = r0.z; dst[3] = r0.w;
        dst[4] = r1.x; dst[5] = r1.y; dst[6] = r1.z; dst[7] = r1.w;
    }
    if (t < 80) dc_lds[t] = dc[t];
    for (int i = t; i < NREP * SEGSTRIDE; i += 256) seg_lds[i] = 0;
    __syncthreads();

    const int jj   = t & 7;        // consecutive lanes -> consecutive j: coalesced x
    const int brow = t >> 3;       // 0..31
    const int b1 = h * 64 + brow;
    const int b2 = b1 + 32;
    int* const segp = &seg_lds[((t >> 3) & (NREP - 1)) * SEGSTRIDE];

    // ---- x rows for both batch elements (share all W reads below)
    const float* xp1 = x + ((size_t)b1 * J_POS + j0 + jj) * 8;
    const float* xp2 = x + ((size_t)b2 * J_POS + j0 + jj) * 8;
    const float4 a0 = *(const float4*)xp1, a1 = *(const float4*)(xp1 + 4);
    const float4 c0 = *(const float4*)xp2, c1 = *(const float4*)(xp2 + 4);
    const float xf1[8] = {a0.x,a0.y,a0.z,a0.w,a1.x,a1.y,a1.z,a1.w};
    const float xf2[8] = {c0.x,c0.y,c0.z,c0.w,c1.x,c1.y,c1.z,c1.w};

    float su1[8] = {0,0,0,0,0,0,0,0};
    float su2[8] = {0,0,0,0,0,0,0,0};
    const float* wbase = &w_lds[jj * WSTRIDE];

    #pragma unroll 1               // keep VGPRs low: one vote-column at a time
    for (int m = 0; m < 4; ++m) {
        float u1[8] = {0,0,0,0,0,0,0,0};
        float u2[8] = {0,0,0,0,0,0,0,0};
        #pragma unroll
        for (int i = 0; i < 8; ++i) {
            const float4 wa = *(const float4*)(wbase + i * 32 + m * 8);
            const float4 wb = *(const float4*)(wbase + i * 32 + m * 8 + 4);
            const float x1 = xf1[i], x2 = xf2[i];
            u1[0] += x1*wa.x; u1[1] += x1*wa.y; u1[2] += x1*wa.z; u1[3] += x1*wa.w;
            u1[4] += x1*wb.x; u1[5] += x1*wb.y; u1[6] += x1*wb.z; u1[7] += x1*wb.w;
            u2[0] += x2*wa.x; u2[1] += x2*wa.y; u2[2] += x2*wa.z; u2[3] += x2*wa.w;
            u2[4] += x2*wb.x; u2[5] += x2*wb.y; u2[6] += x2*wb.z; u2[7] += x2*wb.w;
        }

        // ---- argmax over 10 caps for both votes; dc read as broadcast float4
        float best1 = -3.402823466e38f, best2 = -3.402823466e38f;
        int bc1 = 0, bc2 = 0;
        #pragma unroll
        for (int c = 0; c < 10; ++c) {
            const float4 da = *(const float4*)&dc_lds[c * 8];
            const float4 db = *(const float4*)&dc_lds[c * 8 + 4];
            const float s1 = u1[0]*da.x + u1[1]*da.y + u1[2]*da.z + u1[3]*da.w
                           + u1[4]*db.x + u1[5]*db.y + u1[6]*db.z + u1[7]*db.w;
            const float s2 = u2[0]*da.x + u2[1]*da.y + u2[2]*da.z + u2[3]*da.w
                           + u2[4]*db.x + u2[5]*db.y + u2[6]*db.z + u2[7]*db.w;
            if (s1 > best1) { best1 = s1; bc1 = c; }   // strict > = first max (jnp)
            if (s2 > best2) { best2 = s2; bc2 = c; }
        }

        // ---- native int LDS atomics, fire-and-forget
        const int o1 = bc1 * 9, o2 = bc2 * 9;
        #pragma unroll
        for (int d = 0; d < 8; ++d)
            atomicAdd(&segp[o1 + d], __float2int_rn(u1[d] * SEG_SCALE));
        atomicAdd(&segp[o1 + 8], 1);
        #pragma unroll
        for (int d = 0; d < 8; ++d)
            atomicAdd(&segp[o2 + d], __float2int_rn(u2[d] * SEG_SCALE));
        atomicAdd(&segp[o2 + 8], 1);

        #pragma unroll
        for (int d = 0; d < 8; ++d) { su1[d] += u1[d]; su2[d] += u2[d]; }
    }

    // ---- reduce su across the 8 jj-lanes (same wave)
    #pragma unroll
    for (int d = 0; d < 8; ++d) {
        su1[d] += __shfl_xor(su1[d], 1);
        su1[d] += __shfl_xor(su1[d], 2);
        su1[d] += __shfl_xor(su1[d], 4);
        su2[d] += __shfl_xor(su2[d], 1);
        su2[d] += __shfl_xor(su2[d], 2);
        su2[d] += __shfl_xor(su2[d], 4);
    }
    if (jj == 0) {
        #pragma unroll
        for (int d = 0; d < 8; ++d) {
            s_lds[brow * 8 + d] = su1[d];          // local b = brow
            s_lds[(brow + 32) * 8 + d] = su2[d];   // local b = brow+32
        }
    }
    __syncthreads();

    // ---- flush: seg -> i64 global atomics (exact), cnt -> i32, s -> i64 fixed pt
    if (t < 80) {
        const int o = (t >> 3) * 9 + (t & 7);
        long long v = 0;
        #pragma unroll
        for (int r = 0; r < NREP; ++r) v += seg_lds[r * SEGSTRIDE + o];
        atomicAdd(&ws64[t], (unsigned long long)v);
    } else if (t < 90) {
        const int o = (t - 80) * 9 + 8;
        int v = 0;
        #pragma unroll
        for (int r = 0; r < NREP; ++r) v += seg_lds[r * SEGSTRIDE + o];
        atomicAdd(&wsi[WS_CNT_OFF + (t - 80)], v);
    }
    {
        const int i0 = t * 2;
        const long long v0 = (long long)llrintf(s_lds[i0] * S_SCALE);
        const long long v1 = (long long)llrintf(s_lds[i0 + 1] * S_SCALE);
        atomicAdd(&ws64[WS_S_OFF + h * 512 + i0],     (unsigned long long)v0);
        atomicAdd(&ws64[WS_S_OFF + h * 512 + i0 + 1], (unsigned long long)v1);
    }
}

__global__ __launch_bounds__(256) void finalize_kernel(
    const unsigned long long* __restrict__ ws64,
    const int* __restrict__ wsi,
    const float* __restrict__ dc,
    float* __restrict__ out)       // [0,1280): output  [1280,1360): dc_new
{
    __shared__ float dcn[80];
    __shared__ float sf[1024];
    const int t = threadIdx.x;

    if (t < 80) {
        const int c = t >> 3;
        const float segf = (float)(long long)ws64[t] * INV_SEG_SCALE;
        const float cntf = (float)wsi[WS_CNT_OFF + c];
        const float d0 = dc[t];
        const float nd = d0 + (segf - cntf * d0) * (1.0f / DENOM);
        dcn[t] = nd;
        out[1280 + t] = nd;
    }
    #pragma unroll
    for (int r = 0; r < 4; ++r) {
        const int i = r * 256 + t;
        sf[i] = (float)(long long)ws64[WS_S_OFF + i] * (INV_S_SCALE / NVOTES);
    }
    __syncthreads();

    #pragma unroll
    for (int r = 0; r < 5; ++r) {
        const int idx = r * 256 + t;        // 0..1279
        const int b = idx / 10, c = idx - b * 10;
        float acc = 0.f;
        #pragma unroll
        for (int d = 0; d < 8; ++d) acc += sf[b * 8 + d] * dcn[c * 8 + d];
        out[idx] = acc;
    }
}

extern "C" void kernel_launch(void* const* d_in, const int* in_sizes, int n_in,
                              void* d_out, int out_size, void* d_ws, size_t ws_size,
                              hipStream_t stream) {
    const float* x  = (const float*)d_in[0];
    const float* w  = (const float*)d_in[1];
    const float* dc = (const float*)d_in[2];
    float* out = (float*)d_out;
    unsigned long long* ws64 = (unsigned long long*)d_ws;
    int*   wsi = (int*)d_ws;

    hipMemsetAsync(d_ws, 0, 10240, stream);   // seg + s + counts
    votes_kernel<<<1152, 256, 0, stream>>>(x, w, dc, ws64, wsi);
    finalize_kernel<<<1, 256, 0, stream>>>(ws64, wsi, dc, out);
}